// Round 2
// baseline (17143.263 us; speedup 1.0000x reference)
//
#include <hip/hip_runtime.h>
#include <stdint.h>

#define BATCH 64
#define TSEQ  512
#define INDIM 256
#define HDIM  512
#define GDIM  2048   // 4*H
#define NCLS  1000
#define TCH   64               // time-chunk for xg staging
#define NCHUNK (TSEQ / TCH)    // 8

// ---------------- workspace layout (bytes) ----------------
// h   : [64][512][512] f32 = 64 MB   (in-place: layer l-1 rows overwritten by layer l per chunk)
// xg  : [64][64][2048] f32 = 32 MB   (one chunk)
// c   : [64][512]      f32 = 128 KB  (cell state across chunk launches)
// bar : 24 launches x 64 uints
#define H_OFF   0UL
#define XG_OFF  67108864UL
#define C_OFF   (XG_OFF + 33554432UL)
#define BAR_OFF (C_OFF + 131072UL)
#define WS_NEED (BAR_OFF + 6144UL)

// ---------------- recurrence LDS layout (floats) ----------------
#define W_LDS_F   (512 * 32)       // w_lds[k][32 rows], 64 KB
#define H_STR     18               // padded stride (aligned float2, conflict-free GEMV reads)
#define H_LDS_F   (512 * H_STR)
#define RED_F     (4 * 32 * 17)
#define GATES_F   (32 * 17)
#define C_F       128
#define REC_F     (W_LDS_F + H_LDS_F + RED_F + GATES_F + C_F)   // 28448 floats = 113792 B

__device__ __forceinline__ float sigf(float x) {
    return 1.f / (1.f + __expf(-x));
}
__device__ __forceinline__ float tanh_fast(float x) {
    x = fminf(fmaxf(x, -15.f), 15.f);
    const float e = __expf(2.f * x);
    return (e - 1.f) / (e + 1.f);
}

// =====================================================================
// GEMM (one time-chunk): out[m][n] = A_row(m)[:] . W[n][:] + bih[n]+bhh[n]
// m = b*TCH + t_local ; A_row = A + (b*T_A + t0 + t_local)*K  (in-place h layout)
// 128x128 tile, BK=16, 256 threads, 8x8 per thread.  M = 4096.
// =====================================================================
__global__ __launch_bounds__(256) void gemm_xg(
        const float* __restrict__ A, const float* __restrict__ W,
        const float* __restrict__ bih, const float* __restrict__ bhh,
        float* __restrict__ out, int K, int T_A, int t0)
{
    __shared__ float As[16][132];
    __shared__ float Bs[16][132];
    const int n0 = blockIdx.x << 7;
    const int m0 = blockIdx.y << 7;
    const int tid = threadIdx.x;
    const int tm = tid & 15, tn = tid >> 4;
    float acc[8][8] = {};
    const int nch = K >> 4;
    for (int c = 0; c < nch; c++) {
        const int k0 = c << 4;
        #pragma unroll
        for (int i = 0; i < 2; i++) {
            const int j = tid + (i << 8);     // 0..511
            const int r = j >> 2;             // row 0..127
            const int kq = (j & 3) << 2;      // 0,4,8,12
            const int mr = m0 + r;
            const float* arow = A + ((size_t)(mr >> 6) * T_A + t0 + (mr & 63)) * K;
            const float4 av = *(const float4*)&arow[k0 + kq];
            As[kq + 0][r] = av.x; As[kq + 1][r] = av.y;
            As[kq + 2][r] = av.z; As[kq + 3][r] = av.w;
            const float4 bv = *(const float4*)&W[(size_t)(n0 + r) * K + k0 + kq];
            Bs[kq + 0][r] = bv.x; Bs[kq + 1][r] = bv.y;
            Bs[kq + 2][r] = bv.z; Bs[kq + 3][r] = bv.w;
        }
        __syncthreads();
        #pragma unroll
        for (int k = 0; k < 16; k++) {
            float a[8], b[8];
            *(float4*)&a[0] = *(const float4*)&As[k][tm << 3];
            *(float4*)&a[4] = *(const float4*)&As[k][(tm << 3) + 4];
            *(float4*)&b[0] = *(const float4*)&Bs[k][tn << 3];
            *(float4*)&b[4] = *(const float4*)&Bs[k][(tn << 3) + 4];
            #pragma unroll
            for (int i = 0; i < 8; i++)
                #pragma unroll
                for (int jj = 0; jj < 8; jj++)
                    acc[i][jj] = fmaf(a[i], b[jj], acc[i][jj]);
        }
        __syncthreads();
    }
    #pragma unroll
    for (int i = 0; i < 8; i++) {
        const int m = m0 + (tm << 3) + i;
        float* orow = out + (size_t)m * GDIM + n0 + (tn << 3);
        #pragma unroll
        for (int jj = 0; jj < 8; jj++) {
            const int n = n0 + (tn << 3) + jj;
            orow[jj] = acc[i][jj] + bih[n] + bhh[n];
        }
    }
}

// =====================================================================
// Persistent LSTM recurrence, one layer x one time-chunk (TCH steps).
// grid = 256 WGs x 256 thr (plain launch; 113KB static LDS forces 1 WG/CU
// so all 256 are co-resident).  WG w: group g=w&3 (16 batches),
// slice s=w>>2 (8 h-units -> 32 gate rows, W_hh slice LDS-resident).
// =====================================================================
__global__ __launch_bounds__(256, 1) void lstm_rec(
        const float* __restrict__ Whh,   // [2048][512]
        const float* __restrict__ xg,    // [64][TCH][2048] (chunk)
        float* __restrict__ hout,        // [64][512][512]
        float* __restrict__ cglob,       // [64][512]
        uint32_t* __restrict__ bar,      // this launch's 4 counters, 64B-strided
        int t0)                          // global start step of chunk
{
    __shared__ float smem[REC_F];
    float* w_lds = smem;                  // [512][32]
    float* h_lds = w_lds + W_LDS_F;       // [512][18]
    float* red   = h_lds + H_LDS_F;       // [4][32][17]
    float* gates = red + RED_F;           // [32][17]
    float* c_st  = gates + GATES_F;       // [128]

    const int tid = threadIdx.x;
    const int w   = blockIdx.x;
    const int g   = w & 3;
    const int s   = w >> 2;

    // ---- stage W_hh slice (rows r: gate=r>>3, unit=s*8+(r&7))
    for (int r = 0; r < 32; r++) {
        const int grow = ((r >> 3) * HDIM) + (s << 3) + (r & 7);
        const float* wr = Whh + (size_t)grow * HDIM;
        for (int k = tid; k < HDIM; k += 256)
            w_lds[k * 32 + r] = wr[k];
    }
    if (t0 == 0)
        for (int i = tid; i < H_LDS_F; i += 256) h_lds[i] = 0.f;
    if (tid < C_F) {
        const int b = tid >> 3, u = tid & 7;
        c_st[tid] = (t0 == 0) ? 0.f
                  : cglob[(size_t)((g << 4) + b) * HDIM + (s << 3) + u];
    }
    __syncthreads();

    const int wv   = tid >> 6;
    const int lane = tid & 63;
    const int rq   = lane >> 3;   // rows 4rq..4rq+3
    const int bq   = lane & 7;    // batches 2bq,2bq+1

    const int idx0 = tid,        r0 = idx0 >> 4, b0 = idx0 & 15;
    const int idx1 = tid + 256,  r1 = idx1 >> 4, b1 = idx1 & 15;
    const size_t xoff0 = ((size_t)((g << 4) + b0) * TCH) * GDIM
                       + ((r0 >> 3) * HDIM) + (s << 3) + (r0 & 7);
    const size_t xoff1 = ((size_t)((g << 4) + b1) * TCH) * GDIM
                       + ((r1 >> 3) * HDIM) + (s << 3) + (r1 & 7);

    float xgv0 = xg[xoff0];            // prefetch for t_local=0
    float xgv1 = xg[xoff1];

    for (int t = 0; t < TCH; t++) {
        const int tg = t0 + t;         // global step
        // ---- load h_{tg-1} (group batches) into transposed LDS
        if (tg > 0) {
            const int b = tid >> 4, ut = tid & 15;
            const float* hb = hout + ((size_t)((g << 4) + b) * TSEQ + (tg - 1)) * HDIM;
            #pragma unroll
            for (int i = 0; i < 8; i++) {
                const int u0 = (ut << 2) + (i << 6);
                const float4 hv = *(const float4*)&hb[u0];
                h_lds[(u0 + 0) * H_STR + b] = hv.x;
                h_lds[(u0 + 1) * H_STR + b] = hv.y;
                h_lds[(u0 + 2) * H_STR + b] = hv.z;
                h_lds[(u0 + 3) * H_STR + b] = hv.w;
            }
        }
        __syncthreads();

        // prefetch xg for t+1 (in flight under GEMV)
        const int tn_ = (t + 1 < TCH) ? (t + 1) : t;
        const float nxg0 = xg[xoff0 + (size_t)tn_ * GDIM];
        const float nxg1 = xg[xoff1 + (size_t)tn_ * GDIM];

        // ---- GEMV: wave wv covers k in [128wv, 128wv+128)
        float a00 = 0.f, a01 = 0.f, a10 = 0.f, a11 = 0.f;
        float a20 = 0.f, a21 = 0.f, a30 = 0.f, a31 = 0.f;
        const float* wp = w_lds + ((wv << 7) * 32) + (rq << 2);
        const float* hp = h_lds + ((wv << 7) * H_STR) + (bq << 1);
        #pragma unroll 8
        for (int k = 0; k < 128; k++) {
            const float4 w4 = *(const float4*)wp;
            const float2 h2 = *(const float2*)hp;
            wp += 32; hp += H_STR;
            a00 = fmaf(w4.x, h2.x, a00); a01 = fmaf(w4.x, h2.y, a01);
            a10 = fmaf(w4.y, h2.x, a10); a11 = fmaf(w4.y, h2.y, a11);
            a20 = fmaf(w4.z, h2.x, a20); a21 = fmaf(w4.z, h2.y, a21);
            a30 = fmaf(w4.w, h2.x, a30); a31 = fmaf(w4.w, h2.y, a31);
        }
        {
            float* rp = red + wv * 544 + (rq << 2) * 17 + (bq << 1);
            rp[0]  = a00; rp[1]  = a01;
            rp[17] = a10; rp[18] = a11;
            rp[34] = a20; rp[35] = a21;
            rp[51] = a30; rp[52] = a31;
        }
        __syncthreads();

        // ---- reduce wave partials + xg
        {
            const int o0 = r0 * 17 + b0;
            gates[o0] = red[o0] + red[544 + o0] + red[1088 + o0] + red[1632 + o0] + xgv0;
            const int o1 = r1 * 17 + b1;
            gates[o1] = red[o1] + red[544 + o1] + red[1088 + o1] + red[1632 + o1] + xgv1;
        }
        __syncthreads();

        // ---- pointwise + h store (agent scope, write-through)
        if (tid < 128) {
            const int b = tid >> 3, u = tid & 7;
            const float gi = sigf(gates[u * 17 + b]);
            const float gf = sigf(gates[(8 + u) * 17 + b]);
            const float gg = tanh_fast(gates[(16 + u) * 17 + b]);
            const float go = sigf(gates[(24 + u) * 17 + b]);
            const float c  = fmaf(gf, c_st[tid], gi * gg);
            c_st[tid] = c;
            const float h = go * tanh_fast(c);
            float* hp_out = hout + ((size_t)((g << 4) + b) * TSEQ + tg) * HDIM + (s << 3) + u;
            __hip_atomic_store(hp_out, h, __ATOMIC_RELAXED, __HIP_MEMORY_SCOPE_AGENT);
        }
        xgv0 = nxg0; xgv1 = nxg1;
        __syncthreads();   // drains vmcnt: h stores at LLC before arrive

        // ---- 64-WG group barrier (skip after final step: kernel exit syncs)
        if (t < TCH - 1) {
            if (tid == 0) {
                __hip_atomic_fetch_add(&bar[g * 16], 1u, __ATOMIC_RELEASE,
                                       __HIP_MEMORY_SCOPE_AGENT);
                const uint32_t tgt = 64u * (uint32_t)(t + 1);
                while (__hip_atomic_load(&bar[g * 16], __ATOMIC_RELAXED,
                                         __HIP_MEMORY_SCOPE_AGENT) < tgt)
                    __builtin_amdgcn_s_sleep(2);
                __builtin_amdgcn_fence(__ATOMIC_ACQUIRE, "agent");
            }
            __syncthreads();
        }
    }

    // ---- persist cell state for next chunk
    if (tid < 128) {
        const int b = tid >> 3, u = tid & 7;
        cglob[(size_t)((g << 4) + b) * HDIM + (s << 3) + u] = c_st[tid];
    }
}

// =====================================================================
// FC head: out[b][c] = h[b][T-1][:] . W_fc[c][:] + b_fc[c]
// =====================================================================
__global__ __launch_bounds__(256) void fc_head(
        const float* __restrict__ hbase,   // [64][512][512]
        const float* __restrict__ Wfc,     // [1000][512]
        const float* __restrict__ bfc,
        float* __restrict__ out)           // [64][1000]
{
    __shared__ float hs[HDIM];
    const int b = blockIdx.x;
    const float* hb = hbase + ((size_t)b * TSEQ + (TSEQ - 1)) * HDIM;
    for (int i = threadIdx.x; i < HDIM; i += 256) hs[i] = hb[i];
    __syncthreads();
    const int wave = threadIdx.x >> 6, lane = threadIdx.x & 63;
    for (int c = wave; c < NCLS; c += 4) {
        const float* wr = Wfc + (size_t)c * HDIM;
        float s = 0.f;
        for (int k = lane; k < HDIM; k += 64) s = fmaf(hs[k], wr[k], s);
        #pragma unroll
        for (int off = 32; off > 0; off >>= 1) s += __shfl_down(s, off, 64);
        if (lane == 0) out[b * NCLS + c] = s + bfc[c];
    }
}

// =====================================================================
extern "C" void kernel_launch(void* const* d_in, const int* in_sizes, int n_in,
                              void* d_out, int out_size, void* d_ws, size_t ws_size,
                              hipStream_t stream)
{
    (void)in_sizes; (void)n_in; (void)out_size;
    if (ws_size < WS_NEED) return;   // readable failure instead of OOB fault

    const float* x   = (const float*)d_in[0];
    const float* Wih[3] = {(const float*)d_in[1], (const float*)d_in[5], (const float*)d_in[9]};
    const float* Whh[3] = {(const float*)d_in[2], (const float*)d_in[6], (const float*)d_in[10]};
    const float* bih[3] = {(const float*)d_in[3], (const float*)d_in[7], (const float*)d_in[11]};
    const float* bhh[3] = {(const float*)d_in[4], (const float*)d_in[8], (const float*)d_in[12]};
    const float* Wfc = (const float*)d_in[13];
    const float* bfc = (const float*)d_in[14];
    float* out = (float*)d_out;

    char* ws = (char*)d_ws;
    float* h  = (float*)(ws + H_OFF);
    float* xg = (float*)(ws + XG_OFF);
    float* cg = (float*)(ws + C_OFF);
    uint32_t* bar = (uint32_t*)(ws + BAR_OFF);

    hipMemsetAsync(bar, 0, 6144, stream);

    const dim3 ggrid(GDIM / 128, (BATCH * TCH) / 128), gblk(256);

    for (int l = 0; l < 3; l++) {
        const float* A   = (l == 0) ? x : h;
        const int    K   = (l == 0) ? INDIM : HDIM;
        for (int c = 0; c < NCHUNK; c++) {
            const int t0 = c * TCH;
            gemm_xg<<<ggrid, gblk, 0, stream>>>(A, Wih[l], bih[l], bhh[l], xg, K, TSEQ, t0);
            uint32_t* bp = bar + (l * NCHUNK + c) * 64;
            lstm_rec<<<dim3(256), gblk, 0, stream>>>(Whh[l], xg, h, cg, bp, t0);
        }
    }
    fc_head<<<dim3(64), gblk, 0, stream>>>(h, Wfc, bfc, out);
}

// Round 3
// 16658.968 us; speedup vs baseline: 1.0291x; 1.0291x over previous
//
#include <hip/hip_runtime.h>
#include <stdint.h>

#define BATCH 64
#define TSEQ  512
#define INDIM 256
#define HDIM  512
#define GDIM  2048   // 4*H
#define NCLS  1000
#define TCH   64               // time-chunk for xg staging
#define NCHUNK (TSEQ / TCH)    // 8

// ---------------- workspace layout (bytes) ----------------
// h   : [64][512][512] f32 = 64 MB   (in-place across layers, chunk by chunk)
// xg  : [64][64][2048] f32 = 32 MB   (one chunk)
// c   : [64][512]      f32 = 128 KB  (cell state across chunk launches)
// bar : 24 launches x 128 uints (4 group counters + 4 group flags, 64B-strided)
#define H_OFF   0UL
#define XG_OFF  67108864UL
#define C_OFF   (XG_OFF + 33554432UL)
#define BAR_OFF (C_OFF + 131072UL)
#define BAR_BYTES 12288UL
#define WS_NEED (BAR_OFF + BAR_BYTES)

// ---------------- recurrence LDS layout (floats) ----------------
#define W_LDS_F   (512 * 32)       // w_lds[k][32 rows], 64 KB
#define H_STR     19               // stride 19: transpose stores 2-way (free), reads broadcast
#define H_LDS_F   (512 * H_STR)
#define RED_STR   18               // 2-way on write and read
#define RED_F     (4 * 32 * RED_STR)
#define C_F       128
#define REC_F     (W_LDS_F + H_LDS_F + RED_F + C_F)

__device__ __forceinline__ float sigf(float x) {
    return 1.f / (1.f + __expf(-x));
}
__device__ __forceinline__ float tanh_fast(float x) {
    x = fminf(fmaxf(x, -15.f), 15.f);
    const float e = __expf(2.f * x);
    return (e - 1.f) / (e + 1.f);
}

// =====================================================================
// GEMM (one time-chunk): out[m][n] = A_row(m)[:] . W[n][:] + bih[n]+bhh[n]
// m = b*TCH + t_local ; A_row = A + (b*T_A + t0 + t_local)*K
// 128x128 tile, BK=16, 256 threads, 8x8 per thread.  M = 4096.
// =====================================================================
__global__ __launch_bounds__(256) void gemm_xg(
        const float* __restrict__ A, const float* __restrict__ W,
        const float* __restrict__ bih, const float* __restrict__ bhh,
        float* __restrict__ out, int K, int T_A, int t0)
{
    __shared__ float As[16][132];
    __shared__ float Bs[16][132];
    const int n0 = blockIdx.x << 7;
    const int m0 = blockIdx.y << 7;
    const int tid = threadIdx.x;
    const int tm = tid & 15, tn = tid >> 4;
    float acc[8][8] = {};
    const int nch = K >> 4;
    for (int c = 0; c < nch; c++) {
        const int k0 = c << 4;
        #pragma unroll
        for (int i = 0; i < 2; i++) {
            const int j = tid + (i << 8);     // 0..511
            const int r = j >> 2;             // row 0..127
            const int kq = (j & 3) << 2;      // 0,4,8,12
            const int mr = m0 + r;
            const float* arow = A + ((size_t)(mr >> 6) * T_A + t0 + (mr & 63)) * K;
            const float4 av = *(const float4*)&arow[k0 + kq];
            As[kq + 0][r] = av.x; As[kq + 1][r] = av.y;
            As[kq + 2][r] = av.z; As[kq + 3][r] = av.w;
            const float4 bv = *(const float4*)&W[(size_t)(n0 + r) * K + k0 + kq];
            Bs[kq + 0][r] = bv.x; Bs[kq + 1][r] = bv.y;
            Bs[kq + 2][r] = bv.z; Bs[kq + 3][r] = bv.w;
        }
        __syncthreads();
        #pragma unroll
        for (int k = 0; k < 16; k++) {
            float a[8], b[8];
            *(float4*)&a[0] = *(const float4*)&As[k][tm << 3];
            *(float4*)&a[4] = *(const float4*)&As[k][(tm << 3) + 4];
            *(float4*)&b[0] = *(const float4*)&Bs[k][tn << 3];
            *(float4*)&b[4] = *(const float4*)&Bs[k][(tn << 3) + 4];
            #pragma unroll
            for (int i = 0; i < 8; i++)
                #pragma unroll
                for (int jj = 0; jj < 8; jj++)
                    acc[i][jj] = fmaf(a[i], b[jj], acc[i][jj]);
        }
        __syncthreads();
    }
    #pragma unroll
    for (int i = 0; i < 8; i++) {
        const int m = m0 + (tm << 3) + i;
        float* orow = out + (size_t)m * GDIM + n0 + (tn << 3);
        #pragma unroll
        for (int jj = 0; jj < 8; jj++) {
            const int n = n0 + (tn << 3) + jj;
            orow[jj] = acc[i][jj] + bih[n] + bhh[n];
        }
    }
}

// =====================================================================
// Persistent LSTM recurrence, one layer x one time-chunk (TCH steps).
// grid = 256 WGs x 256 thr.  WG w: group g=w&3 (16 batches), slice s=w>>2
// (8 h-units -> 32 gate rows, W_hh slice LDS-resident).
// Barrier: flag-release — 64 adds to cnt[g], ONE master WG polls cnt and
// writes flag[g]; everyone else polls the read-only flag (no RMW contention).
// =====================================================================
__global__ __launch_bounds__(256, 1) void lstm_rec(
        const float* __restrict__ Whh,   // [2048][512]
        const float* __restrict__ xg,    // [64][TCH][2048] (chunk)
        float* __restrict__ hout,        // [64][512][512]
        float* __restrict__ cglob,       // [64][512]
        uint32_t* __restrict__ bar,      // this launch: cnt[g]=bar[g*16], flag[g]=bar[64+g*16]
        int t0)                          // global start step of chunk
{
    __shared__ float smem[REC_F];
    float* w_lds = smem;                  // [512][32]
    float* h_lds = w_lds + W_LDS_F;       // [512][19]
    float* red   = h_lds + H_LDS_F;       // [4][32][18]
    float* c_st  = red + RED_F;           // [128]

    const int tid = threadIdx.x;
    const int w   = blockIdx.x;
    const int g   = w & 3;
    const int s   = w >> 2;
    uint32_t* cnt = bar + g * 16;
    uint32_t* flg = bar + 64 + g * 16;

    // ---- stage W_hh slice: LDS banks = r (2-way, free)
    {
        const int r  = tid & 31;          // 0..31
        const int kk = tid >> 5;          // 0..7
        const int grow = ((r >> 3) * HDIM) + (s << 3) + (r & 7);
        const float* wr = Whh + (size_t)grow * HDIM;
        for (int k0 = 0; k0 < HDIM; k0 += 8)
            w_lds[(k0 + kk) * 32 + r] = wr[k0 + kk];
    }
    if (t0 == 0)
        for (int i = tid; i < H_LDS_F; i += 256) h_lds[i] = 0.f;
    if (tid < C_F) {
        const int b = tid >> 3, u = tid & 7;
        c_st[tid] = (t0 == 0) ? 0.f
                  : cglob[(size_t)((g << 4) + b) * HDIM + (s << 3) + u];
    }
    __syncthreads();

    const int wv   = tid >> 6;
    const int lane = tid & 63;
    const int rq   = lane >> 3;   // rows 4rq..4rq+3
    const int bq   = lane & 7;    // batches 2bq,2bq+1

    // pointwise-thread mapping (tid<128): u = tid&7, b = tid>>3
    const int pu = tid & 7, pb = tid >> 3;
    const size_t xbase = ((size_t)((g << 4) + pb) * TCH) * GDIM + (s << 3) + pu;

    float xr0 = 0.f, xr1 = 0.f, xr2 = 0.f, xr3 = 0.f;
    if (tid < 128) {                   // prefetch xg for t_local=0
        xr0 = xg[xbase];
        xr1 = xg[xbase + 512];
        xr2 = xg[xbase + 1024];
        xr3 = xg[xbase + 1536];
    }

    for (int t = 0; t < TCH; t++) {
        const int tg = t0 + t;         // global step
        // ---- load h_{tg-1} (group batches) into transposed LDS (2-way stores)
        if (tg > 0) {
            const int b = tid >> 4, ut = tid & 15;
            const float* hb = hout + ((size_t)((g << 4) + b) * TSEQ + (tg - 1)) * HDIM;
            #pragma unroll
            for (int i = 0; i < 8; i++) {
                const int u0 = (ut << 2) + (i << 6);
                const float4 hv = *(const float4*)&hb[u0];
                h_lds[(u0 + 0) * H_STR + b] = hv.x;
                h_lds[(u0 + 1) * H_STR + b] = hv.y;
                h_lds[(u0 + 2) * H_STR + b] = hv.z;
                h_lds[(u0 + 3) * H_STR + b] = hv.w;
            }
        }
        __syncthreads();

        // prefetch xg for t+1 (in flight under GEMV)
        float nx0 = xr0, nx1 = xr1, nx2 = xr2, nx3 = xr3;
        if (tid < 128) {
            const size_t xo = xbase + (size_t)((t + 1 < TCH) ? (t + 1) : t) * GDIM;
            nx0 = xg[xo];
            nx1 = xg[xo + 512];
            nx2 = xg[xo + 1024];
            nx3 = xg[xo + 1536];
        }

        // ---- GEMV: wave wv covers k in [128wv, 128wv+128)
        float a00 = 0.f, a01 = 0.f, a10 = 0.f, a11 = 0.f;
        float a20 = 0.f, a21 = 0.f, a30 = 0.f, a31 = 0.f;
        const float* wp = w_lds + ((wv << 7) * 32) + (rq << 2);
        const float* hp = h_lds + ((wv << 7) * H_STR) + (bq << 1);
        #pragma unroll 8
        for (int k = 0; k < 128; k++) {
            const float4 w4 = *(const float4*)wp;
            const float h2x = hp[0], h2y = hp[1];
            wp += 32; hp += H_STR;
            a00 = fmaf(w4.x, h2x, a00); a01 = fmaf(w4.x, h2y, a01);
            a10 = fmaf(w4.y, h2x, a10); a11 = fmaf(w4.y, h2y, a11);
            a20 = fmaf(w4.z, h2x, a20); a21 = fmaf(w4.z, h2y, a21);
            a30 = fmaf(w4.w, h2x, a30); a31 = fmaf(w4.w, h2y, a31);
        }
        {
            float* rp = red + wv * (32 * RED_STR) + (rq << 2) * RED_STR + (bq << 1);
            rp[0]              = a00; rp[1]              = a01;
            rp[RED_STR]        = a10; rp[RED_STR + 1]    = a11;
            rp[2 * RED_STR]    = a20; rp[2 * RED_STR + 1] = a21;
            rp[3 * RED_STR]    = a30; rp[3 * RED_STR + 1] = a31;
        }
        __syncthreads();

        // ---- merged reduce + pointwise + h store (tid<128: u=pu, b=pb)
        if (tid < 128) {
            const int o = pu * RED_STR + pb;
            const int W1 = 32 * RED_STR, W2 = 64 * RED_STR, W3 = 96 * RED_STR;
            const int gi_o = o, gf_o = o + 8 * RED_STR,
                      gg_o = o + 16 * RED_STR, go_o = o + 24 * RED_STR;
            const float vi = red[gi_o] + red[W1 + gi_o] + red[W2 + gi_o] + red[W3 + gi_o] + xr0;
            const float vf = red[gf_o] + red[W1 + gf_o] + red[W2 + gf_o] + red[W3 + gf_o] + xr1;
            const float vg = red[gg_o] + red[W1 + gg_o] + red[W2 + gg_o] + red[W3 + gg_o] + xr2;
            const float vo = red[go_o] + red[W1 + go_o] + red[W2 + go_o] + red[W3 + go_o] + xr3;
            const float gi = sigf(vi);
            const float gf = sigf(vf);
            const float gg = tanh_fast(vg);
            const float go = sigf(vo);
            const float c  = fmaf(gf, c_st[tid], gi * gg);
            c_st[tid] = c;
            const float h = go * tanh_fast(c);
            float* hp_out = hout + ((size_t)((g << 4) + pb) * TSEQ + tg) * HDIM + (s << 3) + pu;
            __hip_atomic_store(hp_out, h, __ATOMIC_RELAXED, __HIP_MEMORY_SCOPE_AGENT);
        }
        xr0 = nx0; xr1 = nx1; xr2 = nx2; xr3 = nx3;

        // ---- flag-release group barrier (skip after final step: kernel exit syncs)
        if (t < TCH - 1) {
            __syncthreads();           // drains vmcnt: h stores done before arrive
            if (tid == 0) {
                __hip_atomic_fetch_add(cnt, 1u, __ATOMIC_RELEASE,
                                       __HIP_MEMORY_SCOPE_AGENT);
                if (s == 0) {          // master WG of group g
                    const uint32_t tgt = 64u * (uint32_t)(t + 1);
                    while (__hip_atomic_load(cnt, __ATOMIC_RELAXED,
                                             __HIP_MEMORY_SCOPE_AGENT) < tgt)
                        __builtin_amdgcn_s_sleep(1);
                    __hip_atomic_store(flg, (uint32_t)(t + 1), __ATOMIC_RELEASE,
                                       __HIP_MEMORY_SCOPE_AGENT);
                }
                while (__hip_atomic_load(flg, __ATOMIC_RELAXED,
                                         __HIP_MEMORY_SCOPE_AGENT) < (uint32_t)(t + 1))
                    __builtin_amdgcn_s_sleep(1);
                __builtin_amdgcn_fence(__ATOMIC_ACQUIRE, "agent");
            }
            __syncthreads();
        }
    }

    // ---- persist cell state for next chunk
    if (tid < 128) {
        cglob[(size_t)((g << 4) + pb) * HDIM + (s << 3) + pu] = c_st[tid];
    }
}

// =====================================================================
// FC head: out[b][c] = h[b][T-1][:] . W_fc[c][:] + b_fc[c]
// =====================================================================
__global__ __launch_bounds__(256) void fc_head(
        const float* __restrict__ hbase,   // [64][512][512]
        const float* __restrict__ Wfc,     // [1000][512]
        const float* __restrict__ bfc,
        float* __restrict__ out)           // [64][1000]
{
    __shared__ float hs[HDIM];
    const int b = blockIdx.x;
    const float* hb = hbase + ((size_t)b * TSEQ + (TSEQ - 1)) * HDIM;
    for (int i = threadIdx.x; i < HDIM; i += 256) hs[i] = hb[i];
    __syncthreads();
    const int wave = threadIdx.x >> 6, lane = threadIdx.x & 63;
    for (int c = wave; c < NCLS; c += 4) {
        const float* wr = Wfc + (size_t)c * HDIM;
        float s = 0.f;
        for (int k = lane; k < HDIM; k += 64) s = fmaf(hs[k], wr[k], s);
        #pragma unroll
        for (int off = 32; off > 0; off >>= 1) s += __shfl_down(s, off, 64);
        if (lane == 0) out[b * NCLS + c] = s + bfc[c];
    }
}

// =====================================================================
extern "C" void kernel_launch(void* const* d_in, const int* in_sizes, int n_in,
                              void* d_out, int out_size, void* d_ws, size_t ws_size,
                              hipStream_t stream)
{
    (void)in_sizes; (void)n_in; (void)out_size;
    if (ws_size < WS_NEED) return;   // readable failure instead of OOB fault

    const float* x   = (const float*)d_in[0];
    const float* Wih[3] = {(const float*)d_in[1], (const float*)d_in[5], (const float*)d_in[9]};
    const float* Whh[3] = {(const float*)d_in[2], (const float*)d_in[6], (const float*)d_in[10]};
    const float* bih[3] = {(const float*)d_in[3], (const float*)d_in[7], (const float*)d_in[11]};
    const float* bhh[3] = {(const float*)d_in[4], (const float*)d_in[8], (const float*)d_in[12]};
    const float* Wfc = (const float*)d_in[13];
    const float* bfc = (const float*)d_in[14];
    float* out = (float*)d_out;

    char* ws = (char*)d_ws;
    float* h  = (float*)(ws + H_OFF);
    float* xg = (float*)(ws + XG_OFF);
    float* cg = (float*)(ws + C_OFF);
    uint32_t* bar = (uint32_t*)(ws + BAR_OFF);

    hipMemsetAsync(bar, 0, BAR_BYTES, stream);

    const dim3 ggrid(GDIM / 128, (BATCH * TCH) / 128), gblk(256);

    for (int l = 0; l < 3; l++) {
        const float* A   = (l == 0) ? x : h;
        const int    K   = (l == 0) ? INDIM : HDIM;
        for (int c = 0; c < NCHUNK; c++) {
            const int t0 = c * TCH;
            gemm_xg<<<ggrid, gblk, 0, stream>>>(A, Wih[l], bih[l], bhh[l], xg, K, TSEQ, t0);
            uint32_t* bp = bar + (l * NCHUNK + c) * 128;
            lstm_rec<<<dim3(256), gblk, 0, stream>>>(Whh[l], xg, h, cg, bp, t0);
        }
    }
    fc_head<<<dim3(64), gblk, 0, stream>>>(h, Wfc, bfc, out);
}